// Round 1
// baseline (340.325 us; speedup 1.0000x reference)
//
#include <hip/hip_runtime.h>
#include <hip/hip_bf16.h>

typedef __hip_bfloat16 bf16;
typedef float f32x4 __attribute__((ext_vector_type(4)));
typedef short s16x8 __attribute__((ext_vector_type(8)));

// ---------------------------------------------------------------------------
// async global->LDS 16B (direct, no VGPR round trip). Dest must be linear
// wave-uniform base + lane*16 (guide §5).
__device__ __forceinline__ void async_load16(const void* g, void* lds) {
  __builtin_amdgcn_global_load_lds(
      (const __attribute__((address_space(1))) void*)g,
      (__attribute__((address_space(3))) void*)lds, 16, 0, 0);
}

__device__ __forceinline__ void store_out(float* p, float v) { *p = v; }
__device__ __forceinline__ void store_out(bf16* p, float v) { *p = __float2bfloat16(v); }

// ---------------------------------------------------------------------------
// GEMM: C[M,N] = A[M,K] * BT[N,K]^T (+bias). bf16 inputs, f32 accumulate.
// 128x128 tile, BK=32, 4 waves (2x2 of 64x64), 16x16x32 bf16 MFMA.
// Batched via blockIdx.z with element strides sA/sB/sC.
template <typename OutT, bool BIAS>
__global__ void gemm_bt(const bf16* __restrict__ Ag, const bf16* __restrict__ Bg,
                        OutT* __restrict__ Cg, const float* __restrict__ bias,
                        int M, int N, int K,
                        long long sA, long long sB, long long sC) {
  __shared__ bf16 As[128 * 32];
  __shared__ bf16 Bs[128 * 32];
  const bf16* A = Ag + (long long)blockIdx.z * sA;
  const bf16* BT = Bg + (long long)blockIdx.z * sB;
  OutT* C = Cg + (long long)blockIdx.z * sC;

  const int t = threadIdx.x;
  const int lane = t & 63;
  const int wid = t >> 6;
  const int wr = wid >> 1, wc = wid & 1;  // wave 2x2 -> 64x64 each
  const int lo = lane & 15, hi = lane >> 4;
  const long long Kll = K;

  const int arow0 = blockIdx.y * 128;
  const int brow0 = blockIdx.x * 128;

  // staging: 2 chunks of 16B per thread per operand; tile row = 64B
  const int idx0 = t, idx1 = 256 + t;
  const int r0 = idx0 >> 2, c0 = (idx0 & 3) * 8;
  const int r1 = idx1 >> 2, c1 = (idx1 & 3) * 8;

  f32x4 acc[4][4] = {};

  for (int k0 = 0; k0 < K; k0 += 32) {
    __syncthreads();  // previous compute done before overwriting LDS
    async_load16(A + (arow0 + r0) * Kll + k0 + c0, &As[idx0 * 8]);
    async_load16(A + (arow0 + r1) * Kll + k0 + c1, &As[idx1 * 8]);
    async_load16(BT + (brow0 + r0) * Kll + k0 + c0, &Bs[idx0 * 8]);
    async_load16(BT + (brow0 + r1) * Kll + k0 + c1, &Bs[idx1 * 8]);
    __syncthreads();  // compiler drains vmcnt before barrier -> LDS ready

    s16x8 a[4], b[4];
#pragma unroll
    for (int m = 0; m < 4; ++m)
      a[m] = *(const s16x8*)&As[(wr * 64 + m * 16 + lo) * 32 + hi * 8];
#pragma unroll
    for (int n = 0; n < 4; ++n)
      b[n] = *(const s16x8*)&Bs[(wc * 64 + n * 16 + lo) * 32 + hi * 8];
#pragma unroll
    for (int m = 0; m < 4; ++m)
#pragma unroll
      for (int n = 0; n < 4; ++n)
        acc[m][n] = __builtin_amdgcn_mfma_f32_16x16x32_bf16(a[m], b[n], acc[m][n], 0, 0, 0);
  }

  // C/D layout: col = lane&15, row = (lane>>4)*4 + reg  [m89/m91 verified]
#pragma unroll
  for (int n = 0; n < 4; ++n) {
    const int col = brow0 + wc * 64 + n * 16 + lo;
    float bv = 0.f;
    if (BIAS) bv = bias[col];
#pragma unroll
    for (int m = 0; m < 4; ++m) {
      const int row = arow0 + wr * 64 + m * 16 + hi * 4;
#pragma unroll
      for (int j = 0; j < 4; ++j)
        store_out(&C[(long long)(row + j) * N + col], acc[m][n][j] + bv);
    }
  }
}

// ---------------------------------------------------------------------------
__global__ void cvt_f32_bf16(const float* __restrict__ in, bf16* __restrict__ out,
                             long long n4) {
  long long i = (long long)blockIdx.x * 256 + threadIdx.x;
  if (i >= n4) return;
  float4 v = reinterpret_cast<const float4*>(in)[i];
  union { bf16 h[4]; unsigned long long u; } cv;
  cv.h[0] = __float2bfloat16(v.x);
  cv.h[1] = __float2bfloat16(v.y);
  cv.h[2] = __float2bfloat16(v.z);
  cv.h[3] = __float2bfloat16(v.w);
  reinterpret_cast<unsigned long long*>(out)[i] = cv.u;
}

// in f32 [R][C] -> out bf16 [C][R]
__global__ void transpose_f32_to_bf16(const float* __restrict__ in, bf16* __restrict__ out,
                                      int R, int C) {
  __shared__ float tile[32][33];
  const int bx = blockIdx.x * 32;  // input col
  const int by = blockIdx.y * 32;  // input row
  const int tx = threadIdx.x & 31, ty = threadIdx.x >> 5;  // 32x8
#pragma unroll
  for (int i = 0; i < 32; i += 8)
    tile[ty + i][tx] = in[(long long)(by + ty + i) * C + bx + tx];
  __syncthreads();
#pragma unroll
  for (int i = 0; i < 32; i += 8)
    out[(long long)(bx + ty + i) * R + by + tx] = __float2bfloat16(tile[tx][ty + i]);
}

// per-batch: in bf16 [R][C] -> out bf16 [C][R], batch via blockIdx.z
__global__ void transpose_bf16_batched(const bf16* __restrict__ in, bf16* __restrict__ out,
                                       int R, int C) {
  __shared__ bf16 tile[32][33];
  const long long base = (long long)blockIdx.z * R * C;
  const int bx = blockIdx.x * 32;
  const int by = blockIdx.y * 32;
  const int tx = threadIdx.x & 31, ty = threadIdx.x >> 5;
#pragma unroll
  for (int i = 0; i < 32; i += 8)
    tile[ty + i][tx] = in[base + (long long)(by + ty + i) * C + bx + tx];
  __syncthreads();
#pragma unroll
  for (int i = 0; i < 32; i += 8)
    out[base + (long long)(bx + ty + i) * R + by + tx] = tile[tx][ty + i];
}

// ---------------------------------------------------------------------------
// masked scaled softmax: one block per (b,q) row of 2048 scores.
// P = softmax(S * 1/32 with mask -> -inf), written bf16.
__global__ void softmax_mask(const float* __restrict__ S, const int* __restrict__ mask,
                             bf16* __restrict__ P) {
  const int row = blockIdx.x;        // b*1024 + q
  const int b = row >> 10;
  const float* s = S + (long long)row * 2048;
  bf16* p = P + (long long)row * 2048;
  const int* mk = mask + b * 2048;
  const int t = threadIdx.x;
  const int lane = t & 63, wid = t >> 6;

  float4 x0 = reinterpret_cast<const float4*>(s)[t * 2];
  float4 x1 = reinterpret_cast<const float4*>(s)[t * 2 + 1];
  int4 m0 = reinterpret_cast<const int4*>(mk)[t * 2];
  int4 m1 = reinterpret_cast<const int4*>(mk)[t * 2 + 1];

  float v[8];
  v[0] = m0.x ? x0.x * 0.03125f : -INFINITY;
  v[1] = m0.y ? x0.y * 0.03125f : -INFINITY;
  v[2] = m0.z ? x0.z * 0.03125f : -INFINITY;
  v[3] = m0.w ? x0.w * 0.03125f : -INFINITY;
  v[4] = m1.x ? x1.x * 0.03125f : -INFINITY;
  v[5] = m1.y ? x1.y * 0.03125f : -INFINITY;
  v[6] = m1.z ? x1.z * 0.03125f : -INFINITY;
  v[7] = m1.w ? x1.w * 0.03125f : -INFINITY;

  float mx = v[0];
#pragma unroll
  for (int j = 1; j < 8; ++j) mx = fmaxf(mx, v[j]);
  for (int off = 32; off; off >>= 1) mx = fmaxf(mx, __shfl_xor(mx, off, 64));
  __shared__ float redm[4];
  if (lane == 0) redm[wid] = mx;
  __syncthreads();
  mx = fmaxf(fmaxf(redm[0], redm[1]), fmaxf(redm[2], redm[3]));

  float e[8], sum = 0.f;
#pragma unroll
  for (int j = 0; j < 8; ++j) { e[j] = expf(v[j] - mx); sum += e[j]; }
  for (int off = 32; off; off >>= 1) sum += __shfl_xor(sum, off, 64);
  __shared__ float reds[4];
  if (lane == 0) reds[wid] = sum;
  __syncthreads();
  sum = reds[0] + reds[1] + reds[2] + reds[3];
  const float inv = 1.0f / sum;

  union { bf16 h[4]; unsigned long long u; } o0, o1;
#pragma unroll
  for (int j = 0; j < 4; ++j) o0.h[j] = __float2bfloat16(e[j] * inv);
#pragma unroll
  for (int j = 0; j < 4; ++j) o1.h[j] = __float2bfloat16(e[4 + j] * inv);
  reinterpret_cast<unsigned long long*>(p)[t * 2] = o0.u;
  reinterpret_cast<unsigned long long*>(p)[t * 2 + 1] = o1.u;
}

// ---------------------------------------------------------------------------
extern "C" void kernel_launch(void* const* d_in, const int* in_sizes, int n_in,
                              void* d_out, int out_size, void* d_ws, size_t ws_size,
                              hipStream_t stream) {
  const float* query = (const float*)d_in[0];   // [8,1024,1024]
  const float* key_value = (const float*)d_in[1];  // [8,2048,1024]
  const int* key_mask = (const int*)d_in[2];    // [8,2048]
  const float* Wq = (const float*)d_in[3];
  const float* bq = (const float*)d_in[4];
  const float* Wk = (const float*)d_in[5];
  const float* bk = (const float*)d_in[6];
  const float* Wv = (const float*)d_in[7];
  const float* bv = (const float*)d_in[8];
  const float* Wo = (const float*)d_in[9];
  const float* bo = (const float*)d_in[10];
  float* out = (float*)d_out;

  char* ws = (char*)d_ws;
  size_t off = 0;
  auto alloc = [&](size_t bytes) {
    char* p = ws + off;
    off += (bytes + 255) & ~(size_t)255;
    return p;
  };
  bf16* qb = (bf16*)alloc(8192ull * 1024 * 2);     // query bf16
  bf16* kvb = (bf16*)alloc(16384ull * 1024 * 2);   // key_value bf16
  bf16* WqT = (bf16*)alloc(1024ull * 1024 * 2);
  bf16* WkT = (bf16*)alloc(1024ull * 1024 * 2);
  bf16* WvT = (bf16*)alloc(1024ull * 1024 * 2);
  bf16* WoT = (bf16*)alloc(1024ull * 1024 * 2);
  bf16* Qb = (bf16*)alloc(8192ull * 1024 * 2);
  bf16* Kb = (bf16*)alloc(16384ull * 1024 * 2);
  bf16* Vb = (bf16*)alloc(16384ull * 1024 * 2);
  float* S = (float*)alloc(8ull * 1024 * 2048 * 4);
  // aliases (lifetimes disjoint): total ws use ~210 MB
  bf16* VbT = kvb;  // kv bf16 dead after V projection
  bf16* P = Vb;     // Vb dead after transpose
  bf16* Cb = Qb;    // Qb dead after scores GEMM

  // 1. conversions
  cvt_f32_bf16<<<8192, 256, 0, stream>>>(query, qb, 8192ll * 1024 / 4);
  cvt_f32_bf16<<<16384, 256, 0, stream>>>(key_value, kvb, 16384ll * 1024 / 4);
  transpose_f32_to_bf16<<<dim3(32, 32), 256, 0, stream>>>(Wq, WqT, 1024, 1024);
  transpose_f32_to_bf16<<<dim3(32, 32), 256, 0, stream>>>(Wk, WkT, 1024, 1024);
  transpose_f32_to_bf16<<<dim3(32, 32), 256, 0, stream>>>(Wv, WvT, 1024, 1024);
  transpose_f32_to_bf16<<<dim3(32, 32), 256, 0, stream>>>(Wo, WoT, 1024, 1024);

  // 2-4. projections (bias fused)
  gemm_bt<bf16, true><<<dim3(8, 64, 1), 256, 0, stream>>>(qb, WqT, Qb, bq, 8192, 1024, 1024, 0, 0, 0);
  gemm_bt<bf16, true><<<dim3(8, 128, 1), 256, 0, stream>>>(kvb, WkT, Kb, bk, 16384, 1024, 1024, 0, 0, 0);
  gemm_bt<bf16, true><<<dim3(8, 128, 1), 256, 0, stream>>>(kvb, WvT, Vb, bv, 16384, 1024, 1024, 0, 0, 0);

  // 5. V^T per batch: [2048,1024] -> [1024,2048]
  transpose_bf16_batched<<<dim3(32, 64, 8), 256, 0, stream>>>(Vb, VbT, 2048, 1024);

  // 6. scores S = Q K^T (raw; scale applied in softmax)
  gemm_bt<float, false><<<dim3(16, 8, 8), 256, 0, stream>>>(
      Qb, Kb, S, nullptr, 1024, 2048, 1024, 1024ll * 1024, 2048ll * 1024, 1024ll * 2048);

  // 7. masked softmax -> P bf16
  softmax_mask<<<8192, 256, 0, stream>>>(S, key_mask, P);

  // 8. context = P V  (via V^T as BT)
  gemm_bt<bf16, false><<<dim3(8, 8, 8), 256, 0, stream>>>(
      P, VbT, Cb, nullptr, 1024, 1024, 2048, 1024ll * 2048, 1024ll * 2048, 1024ll * 1024);

  // 9. out = Cb Wo + bo (f32 out)
  gemm_bt<float, true><<<dim3(8, 64, 1), 256, 0, stream>>>(Cb, WoT, out, bo, 8192, 1024, 1024, 0, 0, 0);
}

// Round 2
// 302.371 us; speedup vs baseline: 1.1255x; 1.1255x over previous
//
#include <hip/hip_runtime.h>
#include <hip/hip_bf16.h>

typedef __hip_bfloat16 bf16;
typedef float f32x4 __attribute__((ext_vector_type(4)));
typedef short s16x8 __attribute__((ext_vector_type(8)));

// ---------------------------------------------------------------------------
__device__ __forceinline__ void async_load16(const void* g, void* lds) {
  __builtin_amdgcn_global_load_lds(
      (const __attribute__((address_space(1))) void*)g,
      (__attribute__((address_space(3))) void*)lds, 16, 0, 0);
}

__device__ __forceinline__ void store_out(float* p, float v) { *p = v; }
__device__ __forceinline__ void store_out(bf16* p, float v) { *p = __float2bfloat16(v); }

// ---------------------------------------------------------------------------
// C[M,N] = scale*(A[M,K] @ BT[N,K]^T) + bias. bf16 in, f32 acc.
// 128x128 tile, BK=32, double-buffered LDS with next-tile prefetch (T3-min),
// 4 waves (2x2 of 64x64), 16x16x32 bf16 MFMA.
// SWZ=1: batched launch, id&7 = batch (pins batch->XCD).
// SWZ=2: non-batched, chunked XCD swizzle (grid must be %8==0).
template <typename OutT, bool BIAS, int SWZ>
__global__ void gemm_bt(const bf16* __restrict__ Ag, const bf16* __restrict__ Bg,
                        OutT* Cg, const float* __restrict__ biasp, float scale,
                        int K, int lda, int ldb, int ldc, int ntx,
                        long long sA, long long sB, long long sC) {
  __shared__ bf16 As[2][128 * 32];
  __shared__ bf16 Bs[2][128 * 32];

  const int id = blockIdx.x;
  int bz = 0, tile;
  if (SWZ == 1) { bz = id & 7; tile = id >> 3; }
  else if (SWZ == 2) { const int q = gridDim.x >> 3; tile = (id & 7) * q + (id >> 3); }
  else tile = id;
  const int tn = tile % ntx, tm = tile / ntx;

  const bf16* A = Ag + bz * sA;
  const bf16* BT = Bg + bz * sB;
  OutT* C = Cg + bz * sC;

  const int t = threadIdx.x;
  const int lane = t & 63;
  const int wid = t >> 6;
  const int wr = wid >> 1, wc = wid & 1;
  const int lo = lane & 15, hi = lane >> 4;

  const int arow0 = tm * 128, brow0 = tn * 128;

  // staging addresses: 2 chunks of 16B per thread per operand (tile row = 64B)
  const int idx0 = t, idx1 = 256 + t;
  const int r0 = idx0 >> 2, c0 = (idx0 & 3) * 8;
  const int r1 = idx1 >> 2, c1 = (idx1 & 3) * 8;
  const bf16* a0 = A + (long long)(arow0 + r0) * lda + c0;
  const bf16* a1 = A + (long long)(arow0 + r1) * lda + c1;
  const bf16* b0 = BT + (long long)(brow0 + r0) * ldb + c0;
  const bf16* b1 = BT + (long long)(brow0 + r1) * ldb + c1;

  f32x4 acc[4][4] = {};
  const int nt = K >> 5;

  // prologue: stage tile 0
  async_load16(a0, &As[0][idx0 * 8]);
  async_load16(a1, &As[0][idx1 * 8]);
  async_load16(b0, &Bs[0][idx0 * 8]);
  async_load16(b1, &Bs[0][idx1 * 8]);
  __syncthreads();  // drains vmcnt -> buf0 ready

  int cur = 0;
  for (int kt = 0; kt < nt; ++kt) {
    const int nxt = cur ^ 1;
    if (kt + 1 < nt) {  // issue next tile's loads BEFORE computing current
      const int k0 = (kt + 1) << 5;
      async_load16(a0 + k0, &As[nxt][idx0 * 8]);
      async_load16(a1 + k0, &As[nxt][idx1 * 8]);
      async_load16(b0 + k0, &Bs[nxt][idx0 * 8]);
      async_load16(b1 + k0, &Bs[nxt][idx1 * 8]);
    }
    s16x8 a[4], b[4];
#pragma unroll
    for (int m = 0; m < 4; ++m)
      a[m] = *(const s16x8*)&As[cur][(wr * 64 + m * 16 + lo) * 32 + hi * 8];
#pragma unroll
    for (int n = 0; n < 4; ++n)
      b[n] = *(const s16x8*)&Bs[cur][(wc * 64 + n * 16 + lo) * 32 + hi * 8];
#pragma unroll
    for (int m = 0; m < 4; ++m)
#pragma unroll
      for (int n = 0; n < 4; ++n)
        acc[m][n] = __builtin_amdgcn_mfma_f32_16x16x32_bf16(a[m], b[n], acc[m][n], 0, 0, 0);
    __syncthreads();  // vmcnt(0)+lgkmcnt(0)+barrier: next buf ready, reads done
    cur = nxt;
  }

  // C/D layout: col = lane&15, row = (lane>>4)*4 + reg
#pragma unroll
  for (int n = 0; n < 4; ++n) {
    const int col = brow0 + wc * 64 + n * 16 + lo;
    float bv = 0.f;
    if (BIAS) bv = biasp[col];
#pragma unroll
    for (int m = 0; m < 4; ++m) {
      const int row = arow0 + wr * 64 + m * 16 + hi * 4;
#pragma unroll
      for (int j = 0; j < 4; ++j)
        store_out(&C[(long long)(row + j) * ldc + col], acc[m][n][j] * scale + bv);
    }
  }
}

// ---------------------------------------------------------------------------
__global__ void cvt_f32_bf16(const float* __restrict__ in, bf16* __restrict__ out,
                             long long n4) {
  long long i = (long long)blockIdx.x * 256 + threadIdx.x;
  if (i >= n4) return;
  float4 v = reinterpret_cast<const float4*>(in)[i];
  union { bf16 h[4]; unsigned long long u; } cv;
  cv.h[0] = __float2bfloat16(v.x);
  cv.h[1] = __float2bfloat16(v.y);
  cv.h[2] = __float2bfloat16(v.z);
  cv.h[3] = __float2bfloat16(v.w);
  reinterpret_cast<unsigned long long*>(out)[i] = cv.u;
}

// in f32 [R][C] -> out bf16 [C][R] (square-ish, R,C mult of 32)
__global__ void transpose_f32_to_bf16(const float* __restrict__ in, bf16* __restrict__ out,
                                      int R, int C) {
  __shared__ float tile[32][33];
  const int bx = blockIdx.x * 32, by = blockIdx.y * 32;
  const int tx = threadIdx.x & 31, ty = threadIdx.x >> 5;
#pragma unroll
  for (int i = 0; i < 32; i += 8)
    tile[ty + i][tx] = in[(long long)(by + ty + i) * C + bx + tx];
  __syncthreads();
#pragma unroll
  for (int i = 0; i < 32; i += 8)
    out[(long long)(bx + ty + i) * R + by + tx] = __float2bfloat16(tile[tx][ty + i]);
}

// batched bf16 transpose with strides: in [R][ld_in] -> out [C][ld_out]
__global__ void transpose_bf16_b(const bf16* __restrict__ in, bf16* __restrict__ out,
                                 int ld_in, int ld_out, long long sIn, long long sOut) {
  __shared__ bf16 tile[32][33];
  const bf16* ip = in + blockIdx.z * sIn;
  bf16* op = out + blockIdx.z * sOut;
  const int bx = blockIdx.x * 32;  // input col
  const int by = blockIdx.y * 32;  // input row
  const int tx = threadIdx.x & 31, ty = threadIdx.x >> 5;
#pragma unroll
  for (int i = 0; i < 32; i += 8)
    tile[ty + i][tx] = ip[(long long)(by + ty + i) * ld_in + bx + tx];
  __syncthreads();
#pragma unroll
  for (int i = 0; i < 32; i += 8)
    op[(long long)(bx + ty + i) * ld_out + by + tx] = tile[tx][ty + i];
}

__global__ void concat_bias(const float* __restrict__ a, const float* __restrict__ b,
                            float* __restrict__ out) {
  int i = blockIdx.x * 256 + threadIdx.x;
  out[i] = (i < 1024) ? a[i] : b[i - 1024];
}

// ---------------------------------------------------------------------------
// masked softmax over rows of S (bf16, already scaled), IN-PLACE. one block/row.
__global__ void softmax_mask(bf16* __restrict__ S, const int* __restrict__ mask) {
  const int row = blockIdx.x;  // b*1024 + q
  const int b = row >> 10;
  bf16* s = S + (long long)row * 2048;
  const int* mk = mask + b * 2048;
  const int t = threadIdx.x;
  const int lane = t & 63, wid = t >> 6;

  s16x8 xv = reinterpret_cast<const s16x8*>(s)[t];
  int4 m0 = reinterpret_cast<const int4*>(mk)[t * 2];
  int4 m1 = reinterpret_cast<const int4*>(mk)[t * 2 + 1];

  union { s16x8 v; bf16 h[8]; } u;
  u.v = xv;
  float v[8];
  const int mm[8] = {m0.x, m0.y, m0.z, m0.w, m1.x, m1.y, m1.z, m1.w};
#pragma unroll
  for (int j = 0; j < 8; ++j) v[j] = mm[j] ? __bfloat162float(u.h[j]) : -INFINITY;

  float mx = v[0];
#pragma unroll
  for (int j = 1; j < 8; ++j) mx = fmaxf(mx, v[j]);
  for (int off = 32; off; off >>= 1) mx = fmaxf(mx, __shfl_xor(mx, off, 64));
  __shared__ float redm[4];
  if (lane == 0) redm[wid] = mx;
  __syncthreads();
  mx = fmaxf(fmaxf(redm[0], redm[1]), fmaxf(redm[2], redm[3]));

  float e[8], sum = 0.f;
#pragma unroll
  for (int j = 0; j < 8; ++j) { e[j] = __expf(v[j] - mx); sum += e[j]; }
  for (int off = 32; off; off >>= 1) sum += __shfl_xor(sum, off, 64);
  __shared__ float reds[4];
  if (lane == 0) reds[wid] = sum;
  __syncthreads();
  sum = reds[0] + reds[1] + reds[2] + reds[3];
  const float inv = 1.0f / sum;

  union { bf16 h[8]; s16x8 v; } o;
#pragma unroll
  for (int j = 0; j < 8; ++j) o.h[j] = __float2bfloat16(e[j] * inv);
  reinterpret_cast<s16x8*>(s)[t] = o.v;
}

// ---------------------------------------------------------------------------
extern "C" void kernel_launch(void* const* d_in, const int* in_sizes, int n_in,
                              void* d_out, int out_size, void* d_ws, size_t ws_size,
                              hipStream_t stream) {
  const float* query = (const float*)d_in[0];      // [8,1024,1024]
  const float* key_value = (const float*)d_in[1];  // [8,2048,1024]
  const int* key_mask = (const int*)d_in[2];       // [8,2048]
  const float* Wq = (const float*)d_in[3];
  const float* bq = (const float*)d_in[4];
  const float* Wk = (const float*)d_in[5];
  const float* bk = (const float*)d_in[6];
  const float* Wv = (const float*)d_in[7];
  const float* bv = (const float*)d_in[8];
  const float* Wo = (const float*)d_in[9];
  const float* bo = (const float*)d_in[10];
  float* out = (float*)d_out;

  char* ws = (char*)d_ws;
  size_t off = 0;
  auto alloc = [&](size_t bytes) {
    char* p = ws + off;
    off += (bytes + 255) & ~(size_t)255;
    return p;
  };
  bf16* qb   = (bf16*)alloc(8192ull * 1024 * 2);    // query bf16
  bf16* kvb  = (bf16*)alloc(16384ull * 1024 * 2);   // key_value bf16 (later: VT)
  bf16* WqT  = (bf16*)alloc(1024ull * 1024 * 2);
  bf16* WkvT = (bf16*)alloc(2048ull * 1024 * 2);    // [Wk;Wv]^T rows 0-2047
  bf16* WoT  = (bf16*)alloc(1024ull * 1024 * 2);
  float* bkv = (float*)alloc(2048 * 4);
  bf16* Qb   = (bf16*)alloc(8192ull * 1024 * 2);    // later: Cb
  bf16* KVb  = (bf16*)alloc(16384ull * 2048 * 2);   // K | V concat, ld 2048
  bf16* S    = (bf16*)alloc(8ull * 1024 * 2048 * 2);  // scores, softmax in-place
  // aliases (disjoint lifetimes)
  bf16* VT = kvb;  // kv bf16 dead after KV projection; [8][1024][2048]
  bf16* Cb = Qb;   // Qb dead after scores GEMM

  // 1. conversions / weight prep
  cvt_f32_bf16<<<8192, 256, 0, stream>>>(query, qb, 8192ll * 1024 / 4);
  cvt_f32_bf16<<<16384, 256, 0, stream>>>(key_value, kvb, 16384ll * 1024 / 4);
  transpose_f32_to_bf16<<<dim3(32, 32), 256, 0, stream>>>(Wq, WqT, 1024, 1024);
  transpose_f32_to_bf16<<<dim3(32, 32), 256, 0, stream>>>(Wk, WkvT, 1024, 1024);
  transpose_f32_to_bf16<<<dim3(32, 32), 256, 0, stream>>>(Wv, WkvT + 1024ll * 1024, 1024, 1024);
  transpose_f32_to_bf16<<<dim3(32, 32), 256, 0, stream>>>(Wo, WoT, 1024, 1024);
  concat_bias<<<8, 256, 0, stream>>>(bk, bv, bkv);

  // 2. Q projection: [8192,1024] @ Wq + bq -> Qb
  gemm_bt<bf16, true, 2><<<512, 256, 0, stream>>>(
      qb, WqT, Qb, bq, 1.f, 1024, 1024, 1024, 1024, 8, 0, 0, 0);

  // 3. fused K|V projection: [16384,1024] @ [Wk|Wv] + bkv -> KVb [16384,2048]
  gemm_bt<bf16, true, 2><<<2048, 256, 0, stream>>>(
      kvb, WkvT, KVb, bkv, 1.f, 1024, 1024, 1024, 2048, 16, 0, 0, 0);

  // 4. V^T per batch: KVb[:,1024:2048] [2048,1024] -> VT [1024,2048]
  transpose_bf16_b<<<dim3(32, 64, 8), 256, 0, stream>>>(
      KVb + 1024, VT, 2048, 2048, 2048ll * 2048, 1024ll * 2048);

  // 5. scores: S = (Q @ K^T) / 32, bf16 out. batch->XCD pinned.
  gemm_bt<bf16, false, 1><<<1024, 256, 0, stream>>>(
      Qb, KVb, S, nullptr, 0.03125f, 1024, 1024, 2048, 2048, 16,
      1024ll * 1024, 2048ll * 2048, 1024ll * 2048);

  // 6. masked softmax in-place -> P
  softmax_mask<<<8192, 256, 0, stream>>>(S, key_mask);

  // 7. context = P @ V (via VT as BT). batch->XCD pinned.
  gemm_bt<bf16, false, 1><<<512, 256, 0, stream>>>(
      S, VT, Cb, nullptr, 1.f, 2048, 2048, 2048, 1024, 8,
      1024ll * 2048, 1024ll * 2048, 1024ll * 1024);

  // 8. out = Cb @ Wo + bo (f32)
  gemm_bt<float, true, 2><<<512, 256, 0, stream>>>(
      Cb, WoT, out, bo, 1.f, 1024, 1024, 1024, 1024, 8, 0, 0, 0);
}